// Round 5
// baseline (144.738 us; speedup 1.0000x reference)
//
#include <hip/hip_runtime.h>

#define N_NODES 50000
#define N_EDGES 600000
#define D 128
#define LAYERS 2
#define NAL 50048   // N_NODES rounded up to 64
#define CAP 48      // ELL slots per row (degree ~Poisson(12); P(>=48) ~ 1e-15/node)

typedef short bf16x8 __attribute__((ext_vector_type(8)));
typedef float f32x4 __attribute__((ext_vector_type(4)));

__device__ __forceinline__ ushort f2b(float f) {
  uint u = __float_as_uint(f);
  return (ushort)((u + 0x7fffu + ((u >> 16) & 1u)) >> 16);
}
__device__ __forceinline__ float b2f_lo(uint p) { return __uint_as_float(p << 16); }
__device__ __forceinline__ float b2f_hi(uint p) { return __uint_as_float(p & 0xffff0000u); }

// ---------------- prep: zero counts + convert X,W to bf16 (one kernel) ------------
__global__ void k_prep(const float* __restrict__ X, const float* __restrict__ W,
                       int* __restrict__ counts, ushort* __restrict__ Xb,
                       ushort* __restrict__ Wb) {
  int i = blockIdx.x * 256 + threadIdx.x;
  if (i < NAL) counts[i] = 0;
  if (i < N_NODES * D / 4) {
    float4 v = ((const float4*)X)[i];
    ushort4 o;
    o.x = f2b(v.x); o.y = f2b(v.y); o.z = f2b(v.z); o.w = f2b(v.w);
    ((ushort4*)Xb)[i] = o;
  }
  if (i < LAYERS * D * D / 4) {
    float4 v = ((const float4*)W)[i];
    ushort4 o;
    o.x = f2b(v.x); o.y = f2b(v.y); o.z = f2b(v.z); o.w = f2b(v.w);
    ((ushort4*)Wb)[i] = o;
  }
}

// ---------------- ELL build: one pass, atomic cursor ----------------
__global__ void k_fill_ell(const int* __restrict__ row, const int* __restrict__ col,
                           const float* __restrict__ vals, int* __restrict__ counts,
                           int2* __restrict__ ell) {
  int e = blockIdx.x * 256 + threadIdx.x;
  if (e < N_EDGES) {
    int r = row[e];
    int pos = atomicAdd(&counts[r], 1);
    if (pos < CAP)
      ell[(size_t)r * CAP + pos] = make_int2(col[e], __float_as_int(vals[e]));
  }
}

// ---------------- fused layer, register-direct ----------------
// 256 threads = 4 independent waves, no LDS, no barrier. Each wave owns 16
// nodes. Lane (kg=lane>>4, lr=lane&15) gathers node lr's cols
// {c*32 + kg*8 .. +7, c=0..3} -- exactly the MFMA A-fragment it needs.
__global__ __launch_bounds__(256) void k_layer(
    const int* __restrict__ counts, const int2* __restrict__ ell,
    const ushort* __restrict__ Xin, const ushort* __restrict__ Wb,
    const float* __restrict__ bias, const float* __restrict__ temps_l,
    ushort* __restrict__ Yb, float* __restrict__ Yf, int store_f32) {
  const int t = threadIdx.x;
  const int wave = t >> 6;
  const int lane = t & 63;
  const int lr = lane & 15;
  const int kg = lane >> 4;
  const int tile0 = blockIdx.x * 64 + wave * 16;  // first node of this wave's tile
  const int g = tile0 + lr;                        // g < NAL always (782*64=50048)

  float acc[4][8];
  #pragma unroll
  for (int c = 0; c < 4; ++c)
    #pragma unroll
    for (int k = 0; k < 8; ++k) acc[c][k] = 0.f;

  const int2* ep = ell + (size_t)g * CAP;
  int cnt = counts[g];
  if (cnt > CAP) cnt = CAP;
  const int off = kg * 8;

#define FMA8(vv, P, c)                                   \
  {                                                      \
    acc[c][0] = fmaf(vv, b2f_lo((P).x), acc[c][0]);      \
    acc[c][1] = fmaf(vv, b2f_hi((P).x), acc[c][1]);      \
    acc[c][2] = fmaf(vv, b2f_lo((P).y), acc[c][2]);      \
    acc[c][3] = fmaf(vv, b2f_hi((P).y), acc[c][3]);      \
    acc[c][4] = fmaf(vv, b2f_lo((P).z), acc[c][4]);      \
    acc[c][5] = fmaf(vv, b2f_hi((P).z), acc[c][5]);      \
    acc[c][6] = fmaf(vv, b2f_lo((P).w), acc[c][6]);      \
    acc[c][7] = fmaf(vv, b2f_hi((P).w), acc[c][7]);      \
  }

  int j = 0;
  for (; j + 2 <= cnt; j += 2) {
    int4 e = *(const int4*)(ep + j);   // 2 edges
    const ushort* r0 = Xin + ((size_t)e.x << 7) + off;
    const ushort* r1 = Xin + ((size_t)e.z << 7) + off;
    uint4 p00 = *(const uint4*)(r0);
    uint4 p01 = *(const uint4*)(r0 + 32);
    uint4 p02 = *(const uint4*)(r0 + 64);
    uint4 p03 = *(const uint4*)(r0 + 96);
    uint4 p10 = *(const uint4*)(r1);
    uint4 p11 = *(const uint4*)(r1 + 32);
    uint4 p12 = *(const uint4*)(r1 + 64);
    uint4 p13 = *(const uint4*)(r1 + 96);
    float v0 = __int_as_float(e.y);
    float v1 = __int_as_float(e.w);
    FMA8(v0, p00, 0); FMA8(v0, p01, 1); FMA8(v0, p02, 2); FMA8(v0, p03, 3);
    FMA8(v1, p10, 0); FMA8(v1, p11, 1); FMA8(v1, p12, 2); FMA8(v1, p13, 3);
  }
  if (j < cnt) {
    int2 e = ep[j];
    const ushort* r0 = Xin + ((size_t)e.x << 7) + off;
    uint4 p00 = *(const uint4*)(r0);
    uint4 p01 = *(const uint4*)(r0 + 32);
    uint4 p02 = *(const uint4*)(r0 + 64);
    uint4 p03 = *(const uint4*)(r0 + 96);
    float v0 = __int_as_float(e.y);
    FMA8(v0, p00, 0); FMA8(v0, p01, 1); FMA8(v0, p02, 2); FMA8(v0, p03, 3);
  }
#undef FMA8

  // diag row + temps -> bf16 A-fragments (in registers, no LDS)
  bf16x8 afrag[4];
  #pragma unroll
  for (int c = 0; c < 4; ++c) {
    uint4 pr = *(const uint4*)(Xin + ((size_t)g << 7) + c * 32 + off);
    float4 t0 = *(const float4*)(temps_l + c * 32 + off);
    float4 t1 = *(const float4*)(temps_l + c * 32 + off + 4);
    ushort w0 = f2b(b2f_lo(pr.x) - t0.x * acc[c][0]);
    ushort w1 = f2b(b2f_hi(pr.x) - t0.y * acc[c][1]);
    ushort w2 = f2b(b2f_lo(pr.y) - t0.z * acc[c][2]);
    ushort w3 = f2b(b2f_hi(pr.y) - t0.w * acc[c][3]);
    ushort w4 = f2b(b2f_lo(pr.z) - t1.x * acc[c][4]);
    ushort w5 = f2b(b2f_hi(pr.z) - t1.y * acc[c][5]);
    ushort w6 = f2b(b2f_lo(pr.w) - t1.z * acc[c][6]);
    ushort w7 = f2b(b2f_hi(pr.w) - t1.w * acc[c][7]);
    bf16x8 a;
    a[0] = (short)w0; a[1] = (short)w1; a[2] = (short)w2; a[3] = (short)w3;
    a[4] = (short)w4; a[5] = (short)w5; a[6] = (short)w6; a[7] = (short)w7;
    afrag[c] = a;
  }

  // 16x128 GEMM tile via MFMA (one wave does all 8 col-tiles)
  const int crow = kg * 4;
  #pragma unroll
  for (int nt = 0; nt < 8; ++nt) {
    const ushort* wp = Wb + ((size_t)(nt * 16 + lr) << 7) + kg * 8;
    bf16x8 b0 = *(const bf16x8*)(wp);
    bf16x8 b1 = *(const bf16x8*)(wp + 32);
    bf16x8 b2 = *(const bf16x8*)(wp + 64);
    bf16x8 b3 = *(const bf16x8*)(wp + 96);
    f32x4 cacc = {0.f, 0.f, 0.f, 0.f};
    cacc = __builtin_amdgcn_mfma_f32_16x16x32_bf16(afrag[0], b0, cacc, 0, 0, 0);
    cacc = __builtin_amdgcn_mfma_f32_16x16x32_bf16(afrag[1], b1, cacc, 0, 0, 0);
    cacc = __builtin_amdgcn_mfma_f32_16x16x32_bf16(afrag[2], b2, cacc, 0, 0, 0);
    cacc = __builtin_amdgcn_mfma_f32_16x16x32_bf16(afrag[3], b3, cacc, 0, 0, 0);
    const int col = nt * 16 + lr;
    const float bv = bias[col];
    if (store_f32) {
      #pragma unroll
      for (int r = 0; r < 4; ++r) {
        int grow = tile0 + crow + r;
        if (grow < N_NODES)
          Yf[((size_t)grow << 7) + col] = fmaxf(cacc[r] + bv, 0.f);
      }
    } else {
      #pragma unroll
      for (int r = 0; r < 4; ++r) {
        int grow = tile0 + crow + r;   // < NAL always; Yb is padded
        Yb[((size_t)grow << 7) + col] = f2b(fmaxf(cacc[r] + bv, 0.f));
      }
    }
  }
}

extern "C" void kernel_launch(void* const* d_in, const int* in_sizes, int n_in,
                              void* d_out, int out_size, void* d_ws, size_t ws_size,
                              hipStream_t stream) {
  const int*   row   = (const int*)d_in[0];
  const int*   col   = (const int*)d_in[1];
  const float* vals  = (const float*)d_in[2];
  const float* X     = (const float*)d_in[3];
  const float* temps = (const float*)d_in[4];
  const float* W     = (const float*)d_in[5];
  const float* b     = (const float*)d_in[6];
  float* Y = (float*)d_out;

  // workspace layout (16B-aligned sections), ~45 MB total
  int*    counts = (int*)d_ws;                         // NAL ints
  int2*   ell    = (int2*)(counts + NAL);              // NAL*CAP int2 = 19.2 MB
  ushort* Xb     = (ushort*)(ell + (size_t)NAL * CAP); // 12.8 MB
  ushort* Yb     = Xb + (size_t)NAL * D;               // 12.8 MB
  ushort* Wb     = Yb + (size_t)NAL * D;               // 64 KB

  const int eblocks = (N_EDGES + 255) / 256;
  const int pblocks = (N_NODES * D / 4 + 255) / 256;   // covers NAL & W ranges too
  const int lblocks = NAL / 64;                        // 782 blocks x 4 waves

  k_prep<<<pblocks, 256, 0, stream>>>(X, W, counts, Xb, Wb);
  k_fill_ell<<<eblocks, 256, 0, stream>>>(row, col, vals, counts, ell);

  // layer 1: Xb -> Yb (bf16)
  k_layer<<<lblocks, 256, 0, stream>>>(counts, ell, Xb, Wb, b, temps,
                                       Yb, nullptr, 0);
  // layer 2: Yb -> Y (fp32)
  k_layer<<<lblocks, 256, 0, stream>>>(counts, ell, Yb, Wb + D * D, b + D, temps + D,
                                       nullptr, Y, 1);
}

// Round 6
// 129.418 us; speedup vs baseline: 1.1184x; 1.1184x over previous
//
#include <hip/hip_runtime.h>

#define N_NODES 50000
#define N_EDGES 600000
#define D 128
#define LAYERS 2
#define NAL 50048   // N_NODES rounded up to 64
#define CAP 48      // ELL slots per row (fixed input, degree ~Poisson(12); P(max>=48)~0)

typedef short bf16x8 __attribute__((ext_vector_type(8)));
typedef float f32x4 __attribute__((ext_vector_type(4)));

__device__ __forceinline__ ushort f2b(float f) {
  uint u = __float_as_uint(f);
  return (ushort)((u + 0x7fffu + ((u >> 16) & 1u)) >> 16);
}
__device__ __forceinline__ float b2f_lo(uint p) { return __uint_as_float(p << 16); }
__device__ __forceinline__ float b2f_hi(uint p) { return __uint_as_float(p & 0xffff0000u); }

// ---------------- prep: zero counts + convert X,W to bf16 ----------------
__global__ void k_prep(const float* __restrict__ X, const float* __restrict__ W,
                       int* __restrict__ counts, ushort* __restrict__ Xb,
                       ushort* __restrict__ Wb) {
  int i = blockIdx.x * 256 + threadIdx.x;
  if (i < NAL) counts[i] = 0;
  if (i < N_NODES * D / 4) {
    float4 v = ((const float4*)X)[i];
    ushort4 o;
    o.x = f2b(v.x); o.y = f2b(v.y); o.z = f2b(v.z); o.w = f2b(v.w);
    ((ushort4*)Xb)[i] = o;
  }
  if (i < LAYERS * D * D / 4) {
    float4 v = ((const float4*)W)[i];
    ushort4 o;
    o.x = f2b(v.x); o.y = f2b(v.y); o.z = f2b(v.z); o.w = f2b(v.w);
    ((ushort4*)Wb)[i] = o;
  }
}

// ---------------- ELL build: packed 4B edges (bf16 val << 16 | col) ----------------
__global__ void k_fill_ell(const int* __restrict__ row, const int* __restrict__ col,
                           const float* __restrict__ vals, int* __restrict__ counts,
                           uint* __restrict__ ell) {
  int e = blockIdx.x * 256 + threadIdx.x;
  if (e < N_EDGES) {
    int r = row[e];
    int pos = atomicAdd(&counts[r], 1);
    if (pos < CAP)
      ell[(size_t)r * CAP + pos] = ((uint)f2b(vals[e]) << 16) | (uint)col[e];
  }
}

// ---------------- fused layer (round-4 structure + pipelined packed edges) --------
// Block = 256 threads, 16 nodes. Phase A: 16 threads/node gather+accumulate
// (lane owns 16B of the row), software-pipelined 4-edge batches, stage bf16
// result in LDS. Phase B: 4 waves do the 16x128 MFMA GEMM.
__global__ __launch_bounds__(256) void k_layer(
    const int* __restrict__ counts, const uint* __restrict__ ell,
    const ushort* __restrict__ Xin, const ushort* __restrict__ Wb,
    const float* __restrict__ bias, const float* __restrict__ temps_l,
    ushort* __restrict__ Yb, float* __restrict__ Yf, int store_f32) {
  __shared__ ushort Xs[16][136];
  const int t = threadIdx.x;

  // ---- phase A ----
  {
    const int nloc = t >> 4;
    const int c = t & 15;                   // owns cols c*8 .. c*8+7
    const int g = blockIdx.x * 16 + nloc;   // < NAL always (3128 blocks)
    const uint* ep = ell + (size_t)g * CAP;
    int cnt = counts[g];
    if (cnt > CAP) cnt = CAP;
    float a0 = 0.f, a1 = 0.f, a2 = 0.f, a3 = 0.f;
    float a4 = 0.f, a5 = 0.f, a6 = 0.f, a7 = 0.f;
#define EDGE_FMA(v, p)                                             \
    {                                                              \
      a0 = fmaf(v, b2f_lo((p).x), a0); a1 = fmaf(v, b2f_hi((p).x), a1); \
      a2 = fmaf(v, b2f_lo((p).y), a2); a3 = fmaf(v, b2f_hi((p).y), a3); \
      a4 = fmaf(v, b2f_lo((p).z), a4); a5 = fmaf(v, b2f_hi((p).z), a5); \
      a6 = fmaf(v, b2f_lo((p).w), a6); a7 = fmaf(v, b2f_hi((p).w), a7); \
    }
    uint4 eb = *(const uint4*)ep;       // first 4 edges (slots always allocated)
    int j = 0;
    for (; j + 4 <= cnt; j += 4) {
      uint4 en = *(const uint4*)(ep + j + 4);   // prefetch next batch (pad-safe)
      uint4 p0 = *(const uint4*)(Xin + ((size_t)(eb.x & 0xFFFFu) << 7) + c * 8);
      uint4 p1 = *(const uint4*)(Xin + ((size_t)(eb.y & 0xFFFFu) << 7) + c * 8);
      uint4 p2 = *(const uint4*)(Xin + ((size_t)(eb.z & 0xFFFFu) << 7) + c * 8);
      uint4 p3 = *(const uint4*)(Xin + ((size_t)(eb.w & 0xFFFFu) << 7) + c * 8);
      float v0 = b2f_hi(eb.x), v1 = b2f_hi(eb.y);
      float v2 = b2f_hi(eb.z), v3 = b2f_hi(eb.w);
      EDGE_FMA(v0, p0); EDGE_FMA(v1, p1); EDGE_FMA(v2, p2); EDGE_FMA(v3, p3);
      eb = en;
    }
    for (; j < cnt; ++j) {
      uint e = ep[j];
      uint4 p = *(const uint4*)(Xin + ((size_t)(e & 0xFFFFu) << 7) + c * 8);
      float v = b2f_hi(e);
      EDGE_FMA(v, p);
    }
#undef EDGE_FMA
    uint4 pr = *(const uint4*)(Xin + ((size_t)g << 7) + c * 8);
    float4 t0 = *(const float4*)(temps_l + c * 8);
    float4 t1 = *(const float4*)(temps_l + c * 8 + 4);
    uint r0 = (uint)f2b(b2f_lo(pr.x) - t0.x * a0) | ((uint)f2b(b2f_hi(pr.x) - t0.y * a1) << 16);
    uint r1 = (uint)f2b(b2f_lo(pr.y) - t0.z * a2) | ((uint)f2b(b2f_hi(pr.y) - t0.w * a3) << 16);
    uint r2 = (uint)f2b(b2f_lo(pr.z) - t1.x * a4) | ((uint)f2b(b2f_hi(pr.z) - t1.y * a5) << 16);
    uint r3 = (uint)f2b(b2f_lo(pr.w) - t1.z * a6) | ((uint)f2b(b2f_hi(pr.w) - t1.w * a7) << 16);
    *(uint4*)&Xs[nloc][c * 8] = make_uint4(r0, r1, r2, r3);
  }
  __syncthreads();

  // ---- phase B: 16x128 GEMM tile via MFMA ----
  const int wave = t >> 6;
  const int lane = t & 63;
  const int lr = lane & 15;
  const int kg = lane >> 4;

  bf16x8 a0 = *(const bf16x8*)&Xs[lr][0 + kg * 8];
  bf16x8 a1 = *(const bf16x8*)&Xs[lr][32 + kg * 8];
  bf16x8 a2 = *(const bf16x8*)&Xs[lr][64 + kg * 8];
  bf16x8 a3 = *(const bf16x8*)&Xs[lr][96 + kg * 8];

  const int crow = kg * 4;
  #pragma unroll
  for (int q = 0; q < 2; ++q) {
    const int nt = wave * 2 + q;
    const ushort* wp = Wb + ((size_t)(nt * 16 + lr) << 7) + kg * 8;
    bf16x8 b0 = *(const bf16x8*)(wp);
    bf16x8 b1 = *(const bf16x8*)(wp + 32);
    bf16x8 b2 = *(const bf16x8*)(wp + 64);
    bf16x8 b3 = *(const bf16x8*)(wp + 96);
    f32x4 acc = {0.f, 0.f, 0.f, 0.f};
    acc = __builtin_amdgcn_mfma_f32_16x16x32_bf16(a0, b0, acc, 0, 0, 0);
    acc = __builtin_amdgcn_mfma_f32_16x16x32_bf16(a1, b1, acc, 0, 0, 0);
    acc = __builtin_amdgcn_mfma_f32_16x16x32_bf16(a2, b2, acc, 0, 0, 0);
    acc = __builtin_amdgcn_mfma_f32_16x16x32_bf16(a3, b3, acc, 0, 0, 0);
    const int col = nt * 16 + lr;
    const float bv = bias[col];
    if (store_f32) {
      #pragma unroll
      for (int r = 0; r < 4; ++r) {
        int grow = blockIdx.x * 16 + crow + r;
        if (grow < N_NODES)
          Yf[((size_t)grow << 7) + col] = fmaxf(acc[r] + bv, 0.f);
      }
    } else {
      #pragma unroll
      for (int r = 0; r < 4; ++r) {
        int grow = blockIdx.x * 16 + crow + r;   // < NAL always; Yb padded
        Yb[((size_t)grow << 7) + col] = f2b(fmaxf(acc[r] + bv, 0.f));
      }
    }
  }
}

extern "C" void kernel_launch(void* const* d_in, const int* in_sizes, int n_in,
                              void* d_out, int out_size, void* d_ws, size_t ws_size,
                              hipStream_t stream) {
  const int*   row   = (const int*)d_in[0];
  const int*   col   = (const int*)d_in[1];
  const float* vals  = (const float*)d_in[2];
  const float* X     = (const float*)d_in[3];
  const float* temps = (const float*)d_in[4];
  const float* W     = (const float*)d_in[5];
  const float* b     = (const float*)d_in[6];
  float* Y = (float*)d_out;

  // workspace layout (16B-aligned sections), ~35.5 MB total
  int*    counts = (int*)d_ws;                              // NAL ints
  uint*   ell    = (uint*)(counts + NAL);                   // NAL*CAP uint = 9.6 MB
  ushort* Xb     = (ushort*)(ell + (size_t)NAL * CAP + 16); // (+16 pad for prefetch)
  ushort* Yb     = Xb + (size_t)NAL * D;                    // 12.8 MB
  ushort* Wb     = Yb + (size_t)NAL * D;                    // 64 KB

  const int eblocks = (N_EDGES + 255) / 256;
  const int pblocks = (N_NODES * D / 4 + 255) / 256;
  const int lblocks = NAL / 16;                             // 3128

  k_prep<<<pblocks, 256, 0, stream>>>(X, W, counts, Xb, Wb);
  k_fill_ell<<<eblocks, 256, 0, stream>>>(row, col, vals, counts, ell);

  // layer 1: Xb -> Yb (bf16)
  k_layer<<<lblocks, 256, 0, stream>>>(counts, ell, Xb, Wb, b, temps,
                                       Yb, nullptr, 0);
  // layer 2: Yb -> Y (fp32)
  k_layer<<<lblocks, 256, 0, stream>>>(counts, ell, Yb, Wb + D * D, b + D, temps + D,
                                       nullptr, Y, 1);
}

// Round 7
// 119.490 us; speedup vs baseline: 1.2113x; 1.0831x over previous
//
#include <hip/hip_runtime.h>

#define N_NODES 50000
#define N_EDGES 600000
#define D 128
#define LAYERS 2
#define NAL 50048   // N_NODES rounded up to 64
#define CAP 48      // ELL slots per row (fixed input, degree ~Poisson(12); P(max>=48)~5e-9)

typedef short bf16x8 __attribute__((ext_vector_type(8)));
typedef float f32x4 __attribute__((ext_vector_type(4)));

__device__ __forceinline__ ushort f2b(float f) {
  uint u = __float_as_uint(f);
  return (ushort)((u + 0x7fffu + ((u >> 16) & 1u)) >> 16);
}
__device__ __forceinline__ float b2f_lo(uint p) { return __uint_as_float(p << 16); }
__device__ __forceinline__ float b2f_hi(uint p) { return __uint_as_float(p & 0xffff0000u); }

// ---------------- prep: zero counts + convert X,W to bf16 ----------------
__global__ void k_prep(const float* __restrict__ X, const float* __restrict__ W,
                       int* __restrict__ counts, ushort* __restrict__ Xb,
                       ushort* __restrict__ Wb) {
  int i = blockIdx.x * 256 + threadIdx.x;
  if (i < NAL) counts[i] = 0;
  if (i < N_NODES * D / 4) {
    float4 v = ((const float4*)X)[i];
    ushort4 o;
    o.x = f2b(v.x); o.y = f2b(v.y); o.z = f2b(v.z); o.w = f2b(v.w);
    ((ushort4*)Xb)[i] = o;
  }
  if (i < LAYERS * D * D / 4) {
    float4 v = ((const float4*)W)[i];
    ushort4 o;
    o.x = f2b(v.x); o.y = f2b(v.y); o.z = f2b(v.z); o.w = f2b(v.w);
    ((ushort4*)Wb)[i] = o;
  }
}

// ---------------- ELL build: packed 4B edges (bf16 val << 16 | col) ----------------
__global__ void k_fill_ell(const int* __restrict__ row, const int* __restrict__ col,
                           const float* __restrict__ vals, int* __restrict__ counts,
                           uint* __restrict__ ell) {
  int e = blockIdx.x * 256 + threadIdx.x;
  if (e < N_EDGES) {
    int r = row[e];
    int pos = atomicAdd(&counts[r], 1);
    if (pos < CAP)
      ell[(size_t)r * CAP + pos] = ((uint)f2b(vals[e]) << 16) | (uint)col[e];
  }
}

// ---------------- fused layer (16 threads/node gather + MFMA GEMM) --------
// Block = 256 threads, 16 nodes. Phase A: 16 threads/node gather+accumulate
// (lane owns 16B of the row), software-pipelined 4-edge batches, stage bf16
// result in LDS. Phase B: 4 waves do the 16x128 MFMA GEMM.
__global__ __launch_bounds__(256) void k_layer(
    const int* __restrict__ counts, const uint* __restrict__ ell,
    const ushort* __restrict__ Xin, const ushort* __restrict__ Wb,
    const float* __restrict__ bias, const float* __restrict__ temps_l,
    ushort* __restrict__ Yb, float* __restrict__ Yf, int store_f32) {
  __shared__ ushort Xs[16][136];
  const int t = threadIdx.x;

  // ---- phase A ----
  {
    const int nloc = t >> 4;
    const int c = t & 15;                   // owns cols c*8 .. c*8+7
    const int g = blockIdx.x * 16 + nloc;   // < NAL always (3128 blocks)
    const uint* ep = ell + (size_t)g * CAP;
    int cnt = counts[g];
    if (cnt > CAP) cnt = CAP;
    float a0 = 0.f, a1 = 0.f, a2 = 0.f, a3 = 0.f;
    float a4 = 0.f, a5 = 0.f, a6 = 0.f, a7 = 0.f;
#define EDGE_FMA(v, p)                                             \
    {                                                              \
      a0 = fmaf(v, b2f_lo((p).x), a0); a1 = fmaf(v, b2f_hi((p).x), a1); \
      a2 = fmaf(v, b2f_lo((p).y), a2); a3 = fmaf(v, b2f_hi((p).y), a3); \
      a4 = fmaf(v, b2f_lo((p).z), a4); a5 = fmaf(v, b2f_hi((p).z), a5); \
      a6 = fmaf(v, b2f_lo((p).w), a6); a7 = fmaf(v, b2f_hi((p).w), a7); \
    }
    uint4 eb = *(const uint4*)ep;       // first 4 edges (slots always allocated)
    int j = 0;
    for (; j + 4 <= cnt; j += 4) {
      uint4 en = *(const uint4*)(ep + j + 4);   // prefetch next batch (over-read
                                                // lands in Xb region: mapped, safe)
      uint4 p0 = *(const uint4*)(Xin + ((size_t)(eb.x & 0xFFFFu) << 7) + c * 8);
      uint4 p1 = *(const uint4*)(Xin + ((size_t)(eb.y & 0xFFFFu) << 7) + c * 8);
      uint4 p2 = *(const uint4*)(Xin + ((size_t)(eb.z & 0xFFFFu) << 7) + c * 8);
      uint4 p3 = *(const uint4*)(Xin + ((size_t)(eb.w & 0xFFFFu) << 7) + c * 8);
      float v0 = b2f_hi(eb.x), v1 = b2f_hi(eb.y);
      float v2 = b2f_hi(eb.z), v3 = b2f_hi(eb.w);
      EDGE_FMA(v0, p0); EDGE_FMA(v1, p1); EDGE_FMA(v2, p2); EDGE_FMA(v3, p3);
      eb = en;
    }
    for (; j < cnt; ++j) {
      uint e = ep[j];
      uint4 p = *(const uint4*)(Xin + ((size_t)(e & 0xFFFFu) << 7) + c * 8);
      float v = b2f_hi(e);
      EDGE_FMA(v, p);
    }
#undef EDGE_FMA
    uint4 pr = *(const uint4*)(Xin + ((size_t)g << 7) + c * 8);
    float4 t0 = *(const float4*)(temps_l + c * 8);
    float4 t1 = *(const float4*)(temps_l + c * 8 + 4);
    uint r0 = (uint)f2b(b2f_lo(pr.x) - t0.x * a0) | ((uint)f2b(b2f_hi(pr.x) - t0.y * a1) << 16);
    uint r1 = (uint)f2b(b2f_lo(pr.y) - t0.z * a2) | ((uint)f2b(b2f_hi(pr.y) - t0.w * a3) << 16);
    uint r2 = (uint)f2b(b2f_lo(pr.z) - t1.x * a4) | ((uint)f2b(b2f_hi(pr.z) - t1.y * a5) << 16);
    uint r3 = (uint)f2b(b2f_lo(pr.w) - t1.z * a6) | ((uint)f2b(b2f_hi(pr.w) - t1.w * a7) << 16);
    *(uint4*)&Xs[nloc][c * 8] = make_uint4(r0, r1, r2, r3);
  }
  __syncthreads();

  // ---- phase B: 16x128 GEMM tile via MFMA ----
  const int wave = t >> 6;
  const int lane = t & 63;
  const int lr = lane & 15;
  const int kg = lane >> 4;

  bf16x8 a0 = *(const bf16x8*)&Xs[lr][0 + kg * 8];
  bf16x8 a1 = *(const bf16x8*)&Xs[lr][32 + kg * 8];
  bf16x8 a2 = *(const bf16x8*)&Xs[lr][64 + kg * 8];
  bf16x8 a3 = *(const bf16x8*)&Xs[lr][96 + kg * 8];

  const int crow = kg * 4;
  #pragma unroll
  for (int q = 0; q < 2; ++q) {
    const int nt = wave * 2 + q;
    const ushort* wp = Wb + ((size_t)(nt * 16 + lr) << 7) + kg * 8;
    bf16x8 b0 = *(const bf16x8*)(wp);
    bf16x8 b1 = *(const bf16x8*)(wp + 32);
    bf16x8 b2 = *(const bf16x8*)(wp + 64);
    bf16x8 b3 = *(const bf16x8*)(wp + 96);
    f32x4 acc = {0.f, 0.f, 0.f, 0.f};
    acc = __builtin_amdgcn_mfma_f32_16x16x32_bf16(a0, b0, acc, 0, 0, 0);
    acc = __builtin_amdgcn_mfma_f32_16x16x32_bf16(a1, b1, acc, 0, 0, 0);
    acc = __builtin_amdgcn_mfma_f32_16x16x32_bf16(a2, b2, acc, 0, 0, 0);
    acc = __builtin_amdgcn_mfma_f32_16x16x32_bf16(a3, b3, acc, 0, 0, 0);
    const int col = nt * 16 + lr;
    const float bv = bias[col];
    if (store_f32) {
      #pragma unroll
      for (int r = 0; r < 4; ++r) {
        int grow = blockIdx.x * 16 + crow + r;
        if (grow < N_NODES)
          Yf[((size_t)grow << 7) + col] = fmaxf(acc[r] + bv, 0.f);
      }
    } else {
      #pragma unroll
      for (int r = 0; r < 4; ++r) {
        int grow = blockIdx.x * 16 + crow + r;   // < NAL always; Yb padded
        Yb[((size_t)grow << 7) + col] = f2b(fmaxf(acc[r] + bv, 0.f));
      }
    }
  }
}

extern "C" void kernel_launch(void* const* d_in, const int* in_sizes, int n_in,
                              void* d_out, int out_size, void* d_ws, size_t ws_size,
                              hipStream_t stream) {
  const int*   row   = (const int*)d_in[0];
  const int*   col   = (const int*)d_in[1];
  const float* vals  = (const float*)d_in[2];
  const float* X     = (const float*)d_in[3];
  const float* temps = (const float*)d_in[4];
  const float* W     = (const float*)d_in[5];
  const float* b     = (const float*)d_in[6];
  float* Y = (float*)d_out;

  // workspace layout — every section size is a multiple of 256 B, so Xb/Yb
  // rows (256 B) stay cache-line aligned. counts = 200192 B, ell = 9609216 B.
  int*    counts = (int*)d_ws;                         // NAL ints
  uint*   ell    = (uint*)(counts + NAL);              // NAL*CAP uint = 9.6 MB
  ushort* Xb     = (ushort*)(ell + (size_t)NAL * CAP); // 12.8 MB, 256-B aligned
  ushort* Yb     = Xb + (size_t)NAL * D;               // 12.8 MB, 256-B aligned
  ushort* Wb     = Yb + (size_t)NAL * D;               // 64 KB

  const int eblocks = (N_EDGES + 255) / 256;
  const int pblocks = (N_NODES * D / 4 + 255) / 256;
  const int lblocks = NAL / 16;                        // 3128

  k_prep<<<pblocks, 256, 0, stream>>>(X, W, counts, Xb, Wb);
  k_fill_ell<<<eblocks, 256, 0, stream>>>(row, col, vals, counts, ell);

  // layer 1: Xb -> Yb (bf16)
  k_layer<<<lblocks, 256, 0, stream>>>(counts, ell, Xb, Wb, b, temps,
                                       Yb, nullptr, 0);
  // layer 2: Yb -> Y (fp32)
  k_layer<<<lblocks, 256, 0, stream>>>(counts, ell, Yb, Wb + D * D, b + D, temps + D,
                                       nullptr, Y, 1);
}

// Round 9
// 108.675 us; speedup vs baseline: 1.3318x; 1.0995x over previous
//
#include <hip/hip_runtime.h>

#define N_NODES 50000
#define N_EDGES 600000
#define D 128
#define LAYERS 2
#define NAL 50048   // N_NODES rounded up to 64
#define CAP 48      // ELL slots per row (fixed input, degree ~Poisson(12); P(max>=48)~5e-9)

typedef short bf16x8 __attribute__((ext_vector_type(8)));
typedef float f32x4 __attribute__((ext_vector_type(4)));
typedef float f32x2 __attribute__((ext_vector_type(2)));

__device__ __forceinline__ ushort f2b(float f) {
  uint u = __float_as_uint(f);
  return (ushort)((u + 0x7fffu + ((u >> 16) & 1u)) >> 16);
}
__device__ __forceinline__ float b2f_lo(uint p) { return __uint_as_float(p << 16); }
__device__ __forceinline__ float b2f_hi(uint p) { return __uint_as_float(p & 0xffff0000u); }

// ---------------- prep: zero counts + convert X,W to bf16; X to fp8 ----------------
__global__ void k_prep(const float* __restrict__ X, const float* __restrict__ W,
                       int* __restrict__ counts, ushort* __restrict__ Xb,
                       ushort* __restrict__ Wb, uint* __restrict__ Xf8) {
  int i = blockIdx.x * 256 + threadIdx.x;
  if (i < NAL) counts[i] = 0;
  if (i < N_NODES * D / 4) {
    float4 v = ((const float4*)X)[i];
    ushort4 o;
    o.x = f2b(v.x); o.y = f2b(v.y); o.z = f2b(v.z); o.w = f2b(v.w);
    ((ushort4*)Xb)[i] = o;
    int pk = __builtin_amdgcn_cvt_pk_fp8_f32(v.x, v.y, 0, false);
    pk = __builtin_amdgcn_cvt_pk_fp8_f32(v.z, v.w, pk, true);
    Xf8[i] = (uint)pk;
  }
  if (i < LAYERS * D * D / 4) {
    float4 v = ((const float4*)W)[i];
    ushort4 o;
    o.x = f2b(v.x); o.y = f2b(v.y); o.z = f2b(v.z); o.w = f2b(v.w);
    ((ushort4*)Wb)[i] = o;
  }
}

// ---------------- ELL build: packed 4B edges (bf16 val << 16 | col) ----------------
__global__ void k_fill_ell(const int* __restrict__ row, const int* __restrict__ col,
                           const float* __restrict__ vals, int* __restrict__ counts,
                           uint* __restrict__ ell) {
  int e = blockIdx.x * 256 + threadIdx.x;
  if (e < N_EDGES) {
    int r = row[e];
    int pos = atomicAdd(&counts[r], 1);
    if (pos < CAP)
      ell[(size_t)r * CAP + pos] = ((uint)f2b(vals[e]) << 16) | (uint)col[e];
  }
}

// ---------------- fused layer (fp8 gather + bf16 diag/GEMM) ----------------
// Block = 256 threads, 16 nodes. Phase A: 16 threads/node gather from the fp8
// shadow (lane owns 8 B = one half-line of a 128-B row), 4-edge pipelined
// batches; diag row from bf16; stage bf16 result in LDS. Phase B: 4 waves do
// the 16x128 MFMA GEMM; epilogue emits bf16 (+fp8 shadow) or fp32.
__global__ __launch_bounds__(256) void k_layer(
    const int* __restrict__ counts, const uint* __restrict__ ell,
    const ushort* __restrict__ Xin, const uchar* __restrict__ Xg8,
    const ushort* __restrict__ Wb, const float* __restrict__ bias,
    const float* __restrict__ temps_l,
    ushort* __restrict__ Yb, uchar* __restrict__ Yf8,
    float* __restrict__ Yf, int store_f32) {
  __shared__ ushort Xs[16][136];
  const int t = threadIdx.x;

  // ---- phase A ----
  {
    const int nloc = t >> 4;
    const int c = t & 15;                   // owns cols c*8 .. c*8+7
    const int g = blockIdx.x * 16 + nloc;   // < NAL always (3128 blocks)
    const uint* ep = ell + (size_t)g * CAP;
    int cnt = counts[g];
    if (cnt > CAP) cnt = CAP;
    float a0 = 0.f, a1 = 0.f, a2 = 0.f, a3 = 0.f;
    float a4 = 0.f, a5 = 0.f, a6 = 0.f, a7 = 0.f;
#define EDGE_FMA(v, q)                                                  \
    {                                                                   \
      f32x2 f0 = __builtin_amdgcn_cvt_pk_f32_fp8((q).x, false);         \
      f32x2 f1 = __builtin_amdgcn_cvt_pk_f32_fp8((q).x, true);          \
      f32x2 f2 = __builtin_amdgcn_cvt_pk_f32_fp8((q).y, false);         \
      f32x2 f3 = __builtin_amdgcn_cvt_pk_f32_fp8((q).y, true);          \
      a0 = fmaf(v, f0.x, a0); a1 = fmaf(v, f0.y, a1);                   \
      a2 = fmaf(v, f1.x, a2); a3 = fmaf(v, f1.y, a3);                   \
      a4 = fmaf(v, f2.x, a4); a5 = fmaf(v, f2.y, a5);                   \
      a6 = fmaf(v, f3.x, a6); a7 = fmaf(v, f3.y, a7);                   \
    }
    uint4 eb = *(const uint4*)ep;       // first 4 edges (slots always allocated)
    int j = 0;
    for (; j + 4 <= cnt; j += 4) {
      uint4 en = *(const uint4*)(ep + j + 4);   // prefetch next batch (over-read
                                                // lands in next ws section: mapped)
      uint2 q0 = *(const uint2*)(Xg8 + ((size_t)(eb.x & 0xFFFFu) << 7) + c * 8);
      uint2 q1 = *(const uint2*)(Xg8 + ((size_t)(eb.y & 0xFFFFu) << 7) + c * 8);
      uint2 q2 = *(const uint2*)(Xg8 + ((size_t)(eb.z & 0xFFFFu) << 7) + c * 8);
      uint2 q3 = *(const uint2*)(Xg8 + ((size_t)(eb.w & 0xFFFFu) << 7) + c * 8);
      float v0 = b2f_hi(eb.x), v1 = b2f_hi(eb.y);
      float v2 = b2f_hi(eb.z), v3 = b2f_hi(eb.w);
      EDGE_FMA(v0, q0); EDGE_FMA(v1, q1); EDGE_FMA(v2, q2); EDGE_FMA(v3, q3);
      eb = en;
    }
    for (; j < cnt; ++j) {
      uint e = ep[j];
      uint2 q = *(const uint2*)(Xg8 + ((size_t)(e & 0xFFFFu) << 7) + c * 8);
      float v = b2f_hi(e);
      EDGE_FMA(v, q);
    }
#undef EDGE_FMA
    uint4 pr = *(const uint4*)(Xin + ((size_t)g << 7) + c * 8);
    float4 t0 = *(const float4*)(temps_l + c * 8);
    float4 t1 = *(const float4*)(temps_l + c * 8 + 4);
    uint r0 = (uint)f2b(b2f_lo(pr.x) - t0.x * a0) | ((uint)f2b(b2f_hi(pr.x) - t0.y * a1) << 16);
    uint r1 = (uint)f2b(b2f_lo(pr.y) - t0.z * a2) | ((uint)f2b(b2f_hi(pr.y) - t0.w * a3) << 16);
    uint r2 = (uint)f2b(b2f_lo(pr.z) - t1.x * a4) | ((uint)f2b(b2f_hi(pr.z) - t1.y * a5) << 16);
    uint r3 = (uint)f2b(b2f_lo(pr.w) - t1.z * a6) | ((uint)f2b(b2f_hi(pr.w) - t1.w * a7) << 16);
    *(uint4*)&Xs[nloc][c * 8] = make_uint4(r0, r1, r2, r3);
  }
  __syncthreads();

  // ---- phase B: 16x128 GEMM tile via MFMA ----
  const int wave = t >> 6;
  const int lane = t & 63;
  const int lr = lane & 15;
  const int kg = lane >> 4;

  bf16x8 a0 = *(const bf16x8*)&Xs[lr][0 + kg * 8];
  bf16x8 a1 = *(const bf16x8*)&Xs[lr][32 + kg * 8];
  bf16x8 a2 = *(const bf16x8*)&Xs[lr][64 + kg * 8];
  bf16x8 a3 = *(const bf16x8*)&Xs[lr][96 + kg * 8];

  const int crow = kg * 4;
  #pragma unroll
  for (int q = 0; q < 2; ++q) {
    const int nt = wave * 2 + q;
    const ushort* wp = Wb + ((size_t)(nt * 16 + lr) << 7) + kg * 8;
    bf16x8 b0 = *(const bf16x8*)(wp);
    bf16x8 b1 = *(const bf16x8*)(wp + 32);
    bf16x8 b2 = *(const bf16x8*)(wp + 64);
    bf16x8 b3 = *(const bf16x8*)(wp + 96);
    f32x4 acc = {0.f, 0.f, 0.f, 0.f};
    acc = __builtin_amdgcn_mfma_f32_16x16x32_bf16(a0, b0, acc, 0, 0, 0);
    acc = __builtin_amdgcn_mfma_f32_16x16x32_bf16(a1, b1, acc, 0, 0, 0);
    acc = __builtin_amdgcn_mfma_f32_16x16x32_bf16(a2, b2, acc, 0, 0, 0);
    acc = __builtin_amdgcn_mfma_f32_16x16x32_bf16(a3, b3, acc, 0, 0, 0);
    const int col = nt * 16 + lr;
    const float bv = bias[col];
    if (store_f32) {
      #pragma unroll
      for (int r = 0; r < 4; ++r) {
        int grow = blockIdx.x * 16 + crow + r;
        if (grow < N_NODES)
          Yf[((size_t)grow << 7) + col] = fmaxf(acc[r] + bv, 0.f);
      }
    } else {
      #pragma unroll
      for (int r = 0; r < 4; ++r) {
        int grow = blockIdx.x * 16 + crow + r;   // < NAL always; Yb/Yf8 padded
        float o = fmaxf(acc[r] + bv, 0.f);
        Yb[((size_t)grow << 7) + col] = f2b(o);
        int pk = __builtin_amdgcn_cvt_pk_fp8_f32(o, o, 0, false);
        Yf8[((size_t)grow << 7) + col] = (uchar)(pk & 0xff);
      }
    }
  }
}

extern "C" void kernel_launch(void* const* d_in, const int* in_sizes, int n_in,
                              void* d_out, int out_size, void* d_ws, size_t ws_size,
                              hipStream_t stream) {
  const int*   row   = (const int*)d_in[0];
  const int*   col   = (const int*)d_in[1];
  const float* vals  = (const float*)d_in[2];
  const float* X     = (const float*)d_in[3];
  const float* temps = (const float*)d_in[4];
  const float* W     = (const float*)d_in[5];
  const float* b     = (const float*)d_in[6];
  float* Y = (float*)d_out;

  // workspace layout — every section size is a multiple of 256 B, so bf16 rows
  // (256 B) and fp8 rows (128 B) stay cache-line aligned.
  int*    counts = (int*)d_ws;                         // 200192 B
  uint*   ell    = (uint*)(counts + NAL);              // 9.6 MB
  ushort* Xb     = (ushort*)(ell + (size_t)NAL * CAP); // 12.8 MB
  ushort* Yb     = Xb + (size_t)NAL * D;               // 12.8 MB
  ushort* Wb     = Yb + (size_t)NAL * D;               // 64 KB
  uchar*  Xf8    = (uchar*)(Wb + LAYERS * D * D);      // 6.4 MB
  uchar*  Yf8    = Xf8 + (size_t)NAL * D;              // 6.4 MB
  // total ~48.3 MB

  const int eblocks = (N_EDGES + 255) / 256;
  const int pblocks = (N_NODES * D / 4 + 255) / 256;
  const int lblocks = NAL / 16;                        // 3128

  k_prep<<<pblocks, 256, 0, stream>>>(X, W, counts, Xb, Wb, (uint*)Xf8);
  k_fill_ell<<<eblocks, 256, 0, stream>>>(row, col, vals, counts, ell);

  // layer 1: gather Xf8 / diag Xb -> Yb + Yf8
  k_layer<<<lblocks, 256, 0, stream>>>(counts, ell, Xb, Xf8, Wb, b, temps,
                                       Yb, Yf8, nullptr, 0);
  // layer 2: gather Yf8 / diag Yb -> Y (fp32)
  k_layer<<<lblocks, 256, 0, stream>>>(counts, ell, Yb, Yf8, Wb + D * D, b + D,
                                       temps + D, nullptr, nullptr, Y, 1);
}